// Round 3
// baseline (402.733 us; speedup 1.0000x reference)
//
#include <hip/hip_runtime.h>
#include <hip/hip_bf16.h>

// LinearAttention fused pipeline for MI355X (gfx950), bf16 MFMA.
// B=8, C=512, L=8192, H=8, DH=64, HID=512, M1=3*HID=1536.
// R2: fused QKV+ctx kernel (EK/V never hit HBM; k_ctx deleted) with
// double-buffered 2-phase main loop + counted vmcnt(6).

typedef short short8 __attribute__((ext_vector_type(8)));
typedef short short4v __attribute__((ext_vector_type(4)));
typedef float f32x4 __attribute__((ext_vector_type(4)));
typedef unsigned short ushort;

#define SQRT512 22.627416997969522f

__device__ __forceinline__ ushort f2bf(float f){
  union{float f; unsigned u;} v; v.f = f;
  unsigned r = v.u + 0x7fffu + ((v.u >> 16) & 1u);
  return (ushort)(r >> 16);
}

// async global->LDS, 16B per lane; lds dest is wave-uniform base (HW adds lane*16)
__device__ __forceinline__ void gload16(const void* g, void* l){
  __builtin_amdgcn_global_load_lds(
      (const __attribute__((address_space(1))) unsigned int*)(unsigned long long)g,
      (__attribute__((address_space(3))) unsigned int*)(unsigned int)(unsigned long long)l,
      16, 0, 0);
}

// ---------------- K0b: W1[o][c] = w_qkv[o][c] * g1[c] * sqrt(512)  (bf16) ----------------
__global__ void k_prep_w1(const float* __restrict__ wqkv, const float* __restrict__ g1,
                          ushort* __restrict__ W1){
  int i = blockIdx.x * 256 + threadIdx.x;   // 1536*512 exact
  int c = i & 511;
  W1[i] = f2bf(wqkv[i] * g1[c] * SQRT512);
}

// ---------------- K0: transpose x -> Xt[b][l][c] bf16, and invnorm[b][l] ------------------
__global__ __launch_bounds__(256) void k_xt(const float* __restrict__ x,
                                            ushort* __restrict__ Xt,
                                            float* __restrict__ invnorm){
  __shared__ __align__(16) ushort tile[64*132]; // 64 l-rows x 128 c, pitch 132
  __shared__ float ssq[4][64];
  int b = blockIdx.y, lb = blockIdx.x;
  int t = threadIdx.x, lane = t & 63, crow = t >> 6;
  const float* xb = x + ((size_t)b*512)*8192 + (size_t)lb*64;
  float acc = 0.f;
  for(int c0 = 0; c0 < 512; c0 += 128){
    __syncthreads();
    for(int cc = crow; cc < 128; cc += 4){
      float v = xb[(size_t)(c0+cc)*8192 + lane];
      acc += v*v;
      tile[lane*132 + cc] = f2bf(v);
    }
    __syncthreads();
    ushort* dst = Xt + ((size_t)(b*8192 + lb*64))*512 + c0;
    int ch = t & 31;
    for(int r = t >> 5; r < 64; r += 8){
      short4v vv = *(const short4v*)&tile[r*132 + ch*4];
      *(short4v*)(dst + (size_t)r*512 + ch*4) = vv;
    }
  }
  ssq[crow][lane] = acc;
  __syncthreads();
  if(t < 64){
    float s = ssq[0][t] + ssq[1][t] + ssq[2][t] + ssq[3][t];
    invnorm[b*8192 + lb*64 + t] = 1.f / fmaxf(sqrtf(s), 1e-12f);
  }
}

// ---------------- K1: fused QKV GEMM + q-softmax + exp(k) + ctx partials ------------------
// 512 threads / 8 waves, 1 block/CU (96.5 KiB LDS), double-buffered 2-phase.
// Q blocks: 128x256 tile (waves 2x4). KV blocks: 256x128 tile (K-rows + V-rows
// of one head-pair; waves 4x2); epilogue computes ctx = expK @ V^T (K=128) and
// writes per-ct f32 partials to ctxp.
__global__ __launch_bounds__(512,1) void k_qkv(
    const ushort* __restrict__ W1, const ushort* __restrict__ Xt,
    const float* __restrict__ invnorm,
    ushort* __restrict__ Qt, float* __restrict__ ctxp, float* __restrict__ kpart){
  __shared__ __align__(16) union U {
    ushort buf[2][24576];                              // 2 x 48 KiB (A then B)
    struct { ushort P[16384]; ushort Vb[16384]; } e;   // KV epilogue staging
  } S;
  __shared__ float ksum[128];

  int bid = blockIdx.x;                    // 3072
  int wg  = (bid & 7)*384 + (bid >> 3);    // XCD-contiguous: one batch per XCD
  int b   = wg / 384;
  int rem = wg % 384;
  bool isQ = rem < 128;
  int t = threadIdx.x, lane = t & 63, w = t >> 6;
  int rsub = lane >> 3;                    // row within 8-row staging group
  int pc   = (lane & 7) ^ rsub;            // pre-swizzled source chunk

  int r = 0, ct2 = 0, hb = 0, ct = 0;
  const ushort* Abase = W1;
  const ushort* Bbase;
  if(isQ){ r = rem >> 5; ct2 = rem & 31;
    Abase = W1 + (size_t)(r*128)*512;
    Bbase = Xt + ((size_t)(b*8192 + ct2*256))*512;
  } else { int kv = rem - 128; hb = kv >> 6; ct = kv & 63;
    Bbase = Xt + ((size_t)(b*8192 + ct*128))*512;
  }
  if(t < 128) ksum[t] = 0.f;

  f32x4 acc[4][4] = {};

  auto stage = [&](int ks, int cb){
    int goff = ks*64 + pc*8;
    ushort* A  = S.buf[cb];
    ushort* Bl = S.buf[cb] + (isQ ? 8192 : 16384);
    if(isQ){
#pragma unroll
      for(int j = 0; j < 2; ++j){ int m = w*2 + j;      // A: 128 rows
        gload16(Abase + (size_t)(m*8 + rsub)*512 + goff, A + m*512); }
#pragma unroll
      for(int j = 0; j < 4; ++j){ int m = w*4 + j;      // B: 256 rows
        gload16(Bbase + (size_t)(m*8 + rsub)*512 + goff, Bl + m*512); }
    } else {
#pragma unroll
      for(int j = 0; j < 4; ++j){ int m = w*4 + j;      // A: 128 K-rows + 128 V-rows
        int row = (m < 16) ? (512 + hb*128 + m*8 + rsub)
                           : (1024 + hb*128 + (m-16)*8 + rsub);
        gload16(W1 + (size_t)row*512 + goff, A + m*512); }
#pragma unroll
      for(int j = 0; j < 2; ++j){ int m = w*2 + j;      // B: 128 rows
        gload16(Bbase + (size_t)(m*8 + rsub)*512 + goff, Bl + m*512); }
    }
  };

  auto compute = [&](int cb){
    ushort* A  = S.buf[cb];
    ushort* Bl = S.buf[cb] + (isQ ? 8192 : 16384);
    int aw = isQ ? (w >> 2) : (w >> 1);
    int bw = isQ ? (w & 3)  : (w & 1);
#pragma unroll
    for(int kk = 0; kk < 2; ++kk){
      int g = kk*4 + (lane >> 4);
      short8 af[4], bf[4];
#pragma unroll
      for(int m4 = 0; m4 < 4; ++m4){ int ra = aw*64 + m4*16 + (lane & 15);
        af[m4] = *(const short8*)&A[ra*64 + (g ^ (ra & 7))*8]; }
#pragma unroll
      for(int n4 = 0; n4 < 4; ++n4){ int rb = bw*64 + n4*16 + (lane & 15);
        bf[n4] = *(const short8*)&Bl[rb*64 + (g ^ (rb & 7))*8]; }
#pragma unroll
      for(int m4 = 0; m4 < 4; ++m4)
#pragma unroll
        for(int n4 = 0; n4 < 4; ++n4)
          acc[m4][n4] = __builtin_amdgcn_mfma_f32_16x16x32_bf16(af[m4], bf[n4], acc[m4][n4], 0,0,0);
    }
  };

  // 2-phase double-buffered main loop, counted vmcnt (6 loads/wave/step)
  stage(0, 0);
  int cur = 0;
#pragma unroll
  for(int ks = 0; ks < 8; ++ks){
    if(ks < 7) stage(ks + 1, cur ^ 1);
    if(ks < 7) asm volatile("s_waitcnt vmcnt(6)" ::: "memory");
    else       asm volatile("s_waitcnt vmcnt(0)" ::: "memory");
    __builtin_amdgcn_s_barrier();
    compute(cur);
    asm volatile("s_waitcnt lgkmcnt(0)" ::: "memory");
    __builtin_amdgcn_s_barrier();
    cur ^= 1;
  }

  if(isQ){
    int wr = w >> 2, wc = w & 3;
    float cs[4];
    const float* invb = invnorm + b*8192 + ct2*256;
#pragma unroll
    for(int n4 = 0; n4 < 4; ++n4) cs[n4] = invb[wc*64 + n4*16 + (lane & 15)];
    // softmax over this wave's head (64 rows), in registers
    float mx[4] = {-3e38f,-3e38f,-3e38f,-3e38f};
#pragma unroll
    for(int m4 = 0; m4 < 4; ++m4)
#pragma unroll
      for(int n4 = 0; n4 < 4; ++n4)
#pragma unroll
        for(int j = 0; j < 4; ++j){
          float v = acc[m4][n4][j]*cs[n4];
          acc[m4][n4][j] = v;
          mx[n4] = fmaxf(mx[n4], v);
        }
#pragma unroll
    for(int n4 = 0; n4 < 4; ++n4){
      mx[n4] = fmaxf(mx[n4], __shfl_xor(mx[n4], 16));
      mx[n4] = fmaxf(mx[n4], __shfl_xor(mx[n4], 32));
    }
    float sm[4] = {0.f,0.f,0.f,0.f};
#pragma unroll
    for(int m4 = 0; m4 < 4; ++m4)
#pragma unroll
      for(int n4 = 0; n4 < 4; ++n4)
#pragma unroll
        for(int j = 0; j < 4; ++j){
          float e = __expf(acc[m4][n4][j] - mx[n4]);
          acc[m4][n4][j] = e;
          sm[n4] += e;
        }
    float inv[4];
#pragma unroll
    for(int n4 = 0; n4 < 4; ++n4){
      sm[n4] += __shfl_xor(sm[n4], 16);
      sm[n4] += __shfl_xor(sm[n4], 32);
      inv[n4] = 0.125f / sm[n4];             // * dh^-0.5
    }
#pragma unroll
    for(int n4 = 0; n4 < 4; ++n4){
      int col = ct2*256 + wc*64 + n4*16 + (lane & 15);
      ushort* dst = Qt + ((size_t)(b*8192 + col))*512 + r*128 + wr*64 + (lane >> 4)*4;
#pragma unroll
      for(int m4 = 0; m4 < 4; ++m4){
        short4v p;
#pragma unroll
        for(int j = 0; j < 4; ++j) p[j] = (short)f2bf(acc[m4][n4][j]*inv[n4]);
        *(short4v*)(dst + m4*16) = p;
      }
    }
  } else {
    // ---- KV epilogue: exp(K)->P, V->Vb (both LDS, l-chunked+swizzled), rowsums ----
    int wr2 = w >> 1, bw = w & 1;
    bool isK = (w < 4);
    float cs[4];
    const float* invb = invnorm + b*8192 + ct*128;
#pragma unroll
    for(int n4 = 0; n4 < 4; ++n4) cs[n4] = invb[bw*64 + n4*16 + (lane & 15)];
#pragma unroll
    for(int m4 = 0; m4 < 4; ++m4)
#pragma unroll
      for(int j = 0; j < 4; ++j){
        int row = wr2*64 + m4*16 + (lane >> 4)*4 + j;    // 0..255
        float rs = 0.f;
#pragma unroll
        for(int n4 = 0; n4 < 4; ++n4){
          int lcol = bw*64 + n4*16 + (lane & 15);        // 0..127
          float val = acc[m4][n4][j]*cs[n4];
          if(isK){
            float e = __expf(val); rs += e;
            S.e.P[row*128 + ((lcol >> 3) ^ (row & 7))*8 + (lcol & 7)] = f2bf(e);
          } else {
            int er = row - 128;
            S.e.Vb[er*128 + ((lcol >> 3) ^ (er & 7))*8 + (lcol & 7)] = f2bf(val);
          }
        }
        if(isK) atomicAdd(&ksum[row], rs);
      }
    __syncthreads();
    if(t < 128) kpart[(size_t)ct*4096 + b*512 + hb*128 + t] = ksum[t];
    // ---- ctx = P @ Vb^T over l (K=128); wave = (head hq, row-quarter rq) ----
    int hq = w >> 2, rq = w & 3;
    f32x4 c2[4] = {};
#pragma unroll
    for(int kk = 0; kk < 4; ++kk){
      int g = kk*4 + (lane >> 4);
      int da = hq*64 + rq*16 + (lane & 15);
      short8 pa = *(const short8*)&S.e.P[da*128 + (g ^ (da & 7))*8];
#pragma unroll
      for(int n4 = 0; n4 < 4; ++n4){
        int eb = hq*64 + n4*16 + (lane & 15);
        short8 vb = *(const short8*)&S.e.Vb[eb*128 + (g ^ (eb & 7))*8];
        c2[n4] = __builtin_amdgcn_mfma_f32_16x16x32_bf16(pa, vb, c2[n4], 0,0,0);
      }
    }
    float* dst = ctxp + ((size_t)((b*8 + hb*2 + hq)*64 + ct))*4096;
#pragma unroll
    for(int n4 = 0; n4 < 4; ++n4)
#pragma unroll
      for(int j = 0; j < 4; ++j){
        int d64 = rq*16 + (lane >> 4)*4 + j;
        int e   = n4*16 + (lane & 15);
        dst[d64*64 + e] = c2[n4][j];
      }
  }
}

// ---------------- K2: invZ[row] = 1 / sum_ct kpart[ct][row] ------------------------------
__global__ void k_invz(const float* __restrict__ kpart, float* __restrict__ invZ){
  int row = blockIdx.x*256 + threadIdx.x;   // 4096 exact
  float s = 0.f;
  for(int c = 0; c < 64; ++c) s += kpart[(size_t)c*4096 + row];
  invZ[row] = 1.f / s;
}

// ---------------- K3b: reduce ctx partials (64 ct), scale by invZ, fold W_out ------------
__global__ void k_m2(const float* __restrict__ ctxp, const float* __restrict__ invZ,
                     const float* __restrict__ Wout, ushort* __restrict__ M2){
  __shared__ __align__(16) ushort ctxl[4096]; // chunked [g=e/8][d][8]
  int bh = blockIdx.x, b = bh >> 3, h = bh & 7;
  int t = threadIdx.x, lane = t & 63, w = t >> 6;  // 512 threads, 8 waves
  for(int i = t; i < 4096; i += 512){
    float s = 0.f;
    for(int sp = 0; sp < 64; ++sp) s += ctxp[((size_t)(bh*64 + sp))*4096 + i];
    int d = i >> 6, e = i & 63;
    s *= invZ[bh*64 + d];
    ctxl[(e >> 3)*512 + d*8 + (e & 7)] = f2bf(s);
  }
  __syncthreads();
  f32x4 acc[4][4] = {};
#pragma unroll
  for(int kk = 0; kk < 2; ++kk){
    int g = kk*4 + (lane >> 4);
    short8 bf[4];
#pragma unroll
    for(int n4 = 0; n4 < 4; ++n4)
      bf[n4] = *(const short8*)&ctxl[g*512 + (n4*16 + (lane & 15))*8];
    int e0 = (lane >> 4)*8 + kk*32;
#pragma unroll
    for(int m4 = 0; m4 < 4; ++m4){
      int o = w*64 + m4*16 + (lane & 15);
      const float* wp = Wout + (size_t)o*512 + h*64 + e0;
      float4 w0 = *(const float4*)(wp);
      float4 w1 = *(const float4*)(wp + 4);
      short8 af;
      af[0]=(short)f2bf(w0.x); af[1]=(short)f2bf(w0.y); af[2]=(short)f2bf(w0.z); af[3]=(short)f2bf(w0.w);
      af[4]=(short)f2bf(w1.x); af[5]=(short)f2bf(w1.y); af[6]=(short)f2bf(w1.z); af[7]=(short)f2bf(w1.w);
#pragma unroll
      for(int n4 = 0; n4 < 4; ++n4)
        acc[m4][n4] = __builtin_amdgcn_mfma_f32_16x16x32_bf16(af, bf[n4], acc[m4][n4], 0,0,0);
    }
  }
  ushort* dst = M2 + (size_t)b*512*512 + h*64;
#pragma unroll
  for(int m4 = 0; m4 < 4; ++m4)
#pragma unroll
    for(int n4 = 0; n4 < 4; ++n4)
#pragma unroll
      for(int j = 0; j < 4; ++j){
        int o = w*64 + m4*16 + (lane >> 4)*4 + j;
        int d = n4*16 + (lane & 15);
        dst[(size_t)o*512 + d] = f2bf(acc[m4][n4][j]);
      }
}

// ---------------- K4: out = rmsnorm(M2_b @ Q + b_out, g2), tall tile 512x64, K=512 --------
__global__ __launch_bounds__(512,2) void k_out(const ushort* __restrict__ M2,
                                               const ushort* __restrict__ Qt,
                                               const float* __restrict__ bout,
                                               const float* __restrict__ g2,
                                               float* __restrict__ out){
  __shared__ __align__(16) ushort A[16384];  // 512 rows x 32 elems = 32 KiB
  __shared__ __align__(16) ushort Bs[2048];  // 64 rows x 32 elems
  __shared__ float colss[64];
  __shared__ float bo[512], gg[512];
  int bid = blockIdx.x;                      // 1024
  int wg = (bid & 7)*128 + (bid >> 3);       // XCD-contiguous per batch
  int b = wg >> 7, lb = wg & 127;
  int t = threadIdx.x, lane = t & 63, w = t >> 6;  // 8 waves
  bo[t & 511] = bout[t & 511];
  gg[t & 511] = g2[t & 511];
  if(t < 64) colss[t] = 0.f;
  const ushort* Abase = M2 + (size_t)b*262144;
  const ushort* Bbase = Qt + ((size_t)(b*8192 + lb*64))*512;
  int rsub = lane >> 2;                      // 0..15 (row within 16-row group)
  int pc   = (lane & 3) ^ ((lane >> 3) & 3); // pre-swizzled source chunk
  f32x4 acc[4][4] = {};
  for(int ks = 0; ks < 16; ++ks){
    int goff = ks*32 + pc*8;
#pragma unroll
    for(int j = 0; j < 4; ++j){
      int m = w*4 + j;                       // 0..31, 16 rows each
      gload16(Abase + (size_t)(m*16 + rsub)*512 + goff, &A[m*512]);
    }
    if(w >= 4){
      int m = w - 4;                         // 0..3, 16 rows each
      gload16(Bbase + (size_t)(m*16 + rsub)*512 + goff, &Bs[m*512]);
    }
    __syncthreads();
    int g = lane >> 4;
    short8 bf[4];
#pragma unroll
    for(int n4 = 0; n4 < 4; ++n4){
      int rb = n4*16 + (lane & 15);
      bf[n4] = *(const short8*)&Bs[rb*32 + (g ^ ((rb >> 1) & 3))*8];
    }
#pragma unroll
    for(int m4 = 0; m4 < 4; ++m4){
      int ra = w*64 + m4*16 + (lane & 15);
      short8 af = *(const short8*)&A[ra*32 + (g ^ ((ra >> 1) & 3))*8];
#pragma unroll
      for(int n4 = 0; n4 < 4; ++n4)
        acc[m4][n4] = __builtin_amdgcn_mfma_f32_16x16x32_bf16(af, bf[n4], acc[m4][n4], 0,0,0);
    }
    __syncthreads();
  }
  // bias + column sumsq
  float ps[4] = {0.f,0.f,0.f,0.f};
#pragma unroll
  for(int m4 = 0; m4 < 4; ++m4)
#pragma unroll
    for(int j = 0; j < 4; ++j){
      int o = w*64 + m4*16 + (lane >> 4)*4 + j;
      float bb = bo[o];
#pragma unroll
      for(int n4 = 0; n4 < 4; ++n4){
        float v = acc[m4][n4][j] + bb;
        acc[m4][n4][j] = v;
        ps[n4] += v*v;
      }
    }
#pragma unroll
  for(int n4 = 0; n4 < 4; ++n4) atomicAdd(&colss[n4*16 + (lane & 15)], ps[n4]);
  __syncthreads();
  float csc[4];
#pragma unroll
  for(int n4 = 0; n4 < 4; ++n4)
    csc[n4] = SQRT512 / fmaxf(sqrtf(colss[n4*16 + (lane & 15)]), 1e-12f);
  float* obase = out + ((size_t)b*512)*8192 + lb*64;
#pragma unroll
  for(int m4 = 0; m4 < 4; ++m4)
#pragma unroll
    for(int j = 0; j < 4; ++j){
      int o = w*64 + m4*16 + (lane >> 4)*4 + j;
      float gv = gg[o];
#pragma unroll
      for(int n4 = 0; n4 < 4; ++n4)
        obase[(size_t)o*8192 + n4*16 + (lane & 15)] = acc[m4][n4][j]*csc[n4]*gv;
    }
}

extern "C" void kernel_launch(void* const* d_in, const int* in_sizes, int n_in,
                              void* d_out, int out_size, void* d_ws, size_t ws_size,
                              hipStream_t stream){
  const float* x    = (const float*)d_in[0];
  const float* g1   = (const float*)d_in[1];
  const float* wqkv = (const float*)d_in[2];
  const float* wout = (const float*)d_in[3];
  const float* bout = (const float*)d_in[4];
  const float* g2   = (const float*)d_in[5];
  float* out = (float*)d_out;
  char* ws = (char*)d_ws;
  const size_t MB = 1024*1024;
  ushort* Qt      = (ushort*)(ws);              // 64 MiB  [b][l][512]
  float*  ctxp    = (float*) (ws + 64*MB);      // 67 MiB  [bh][ct][64][64] f32
  ushort* W1      = (ushort*)(ws + 132*MB);     // 1.5 MiB
  float*  invnorm = (float*) (ws + 134*MB);     // 256 KiB
  float*  kpart   = (float*) (ws + 135*MB);     // 1 MiB [64 ct][4096 rows]
  float*  invZ    = (float*) (ws + 136*MB);     // 16 KiB
  ushort* M2      = (ushort*)(ws + 137*MB);     // 4 MiB  [b][512][512]
  // d_out doubles as scratch until k_out: Xt in first half
  ushort* Xt = (ushort*)d_out;

  k_prep_w1<<<3072, 256, 0, stream>>>(wqkv, g1, W1);
  k_xt<<<dim3(128, 8), 256, 0, stream>>>(x, Xt, invnorm);
  k_qkv<<<3072, 512, 0, stream>>>(W1, Xt, invnorm, Qt, ctxp, kpart);
  k_invz<<<16, 256, 0, stream>>>(kpart, invZ);
  k_m2<<<64, 512, 0, stream>>>(ctxp, invZ, wout, M2);
  k_out<<<1024, 512, 0, stream>>>(M2, Qt, bout, g2, out);
}